// Round 1
// baseline (10235.275 us; speedup 1.0000x reference)
//
#include <hip/hip_runtime.h>
#include <math.h>

// Problem constants (match reference)
#define FMC   512
#define DIMX  1024
#define NCC   157
#define NTOK  10
#define NHEAD 4
#define BBATCH 8
#define TTIME 4096
#define NLAYERS 5

// ---------------------------------------------------------------------------
// GEMM: C[b,m,t] = sum_k W[m,k] * X[b,k,t]  (+bias[m]) (+resid[b,m,t]) (*mask[b,t])
// Tile 64x64, BK=16, 256 threads, 4x4 micro-tile, fp32.
// ---------------------------------------------------------------------------
#define BM 64
#define BN 64
#define BK 16

template <int HAS_BIAS, int HAS_RESID, int HAS_MASK>
__global__ __launch_bounds__(256) void gemm_wx(
    const float* __restrict__ W, const float* __restrict__ X, float* __restrict__ C,
    const float* __restrict__ bias, const float* __restrict__ resid,
    const float* __restrict__ mask, int M, int K)
{
    const int b  = blockIdx.z;
    const int m0 = blockIdx.y * BM;
    const int t0 = blockIdx.x * BN;
    const float* Xb = X + (size_t)b * K * TTIME;
    float* Cb = C + (size_t)b * M * TTIME;

    __shared__ float Ws[BK][BM];
    __shared__ float Xs[BK][BN];

    const int tid = threadIdx.x;
    const int tx = tid & 15;   // t-tile quadrant
    const int ty = tid >> 4;   // m-tile quadrant

    float acc[4][4] = {};

    const int wl_m = tid >> 2;         // 0..63
    const int wl_k = (tid & 3) * 4;    // 0,4,8,12
    const int xl_k = tid >> 4;         // 0..15
    const int xl_t = (tid & 15) * 4;   // 0..60

    for (int k0 = 0; k0 < K; k0 += BK) {
        // W tile (guard m for M=157 case)
        float4 wv;
        int gm = m0 + wl_m;
        if (gm < M) wv = *(const float4*)&W[(size_t)gm * K + k0 + wl_k];
        else        wv = make_float4(0.f, 0.f, 0.f, 0.f);
        Ws[wl_k + 0][wl_m] = wv.x;
        Ws[wl_k + 1][wl_m] = wv.y;
        Ws[wl_k + 2][wl_m] = wv.z;
        Ws[wl_k + 3][wl_m] = wv.w;
        // X tile (T always multiple of 64, K multiple of 16)
        float4 xv = *(const float4*)&Xb[(size_t)(k0 + xl_k) * TTIME + t0 + xl_t];
        *(float4*)&Xs[xl_k][xl_t] = xv;
        __syncthreads();

#pragma unroll
        for (int k = 0; k < BK; ++k) {
            float4 av = *(const float4*)&Ws[k][ty * 4];
            float4 xq = *(const float4*)&Xs[k][tx * 4];
            acc[0][0] += av.x * xq.x; acc[0][1] += av.x * xq.y;
            acc[0][2] += av.x * xq.z; acc[0][3] += av.x * xq.w;
            acc[1][0] += av.y * xq.x; acc[1][1] += av.y * xq.y;
            acc[1][2] += av.y * xq.z; acc[1][3] += av.y * xq.w;
            acc[2][0] += av.z * xq.x; acc[2][1] += av.z * xq.y;
            acc[2][2] += av.z * xq.z; acc[2][3] += av.z * xq.w;
            acc[3][0] += av.w * xq.x; acc[3][1] += av.w * xq.y;
            acc[3][2] += av.w * xq.z; acc[3][3] += av.w * xq.w;
        }
        __syncthreads();
    }

#pragma unroll
    for (int i = 0; i < 4; ++i) {
        int gm = m0 + ty * 4 + i;
        if (gm >= M) continue;
        float bv = HAS_BIAS ? bias[gm] : 0.f;
        float4 r;
        float v0 = acc[i][0] + bv, v1 = acc[i][1] + bv, v2 = acc[i][2] + bv, v3 = acc[i][3] + bv;
        if (HAS_RESID) {
            const float* rr = resid + (size_t)b * M * TTIME + (size_t)gm * TTIME + t0 + tx * 4;
            v0 += rr[0]; v1 += rr[1]; v2 += rr[2]; v3 += rr[3];
        }
        if (HAS_MASK) {
            const float* mm = mask + (size_t)b * TTIME + t0 + tx * 4;
            v0 *= mm[0]; v1 *= mm[1]; v2 *= mm[2]; v3 *= mm[3];
        }
        r.x = v0; r.y = v1; r.z = v2; r.w = v3;
        *(float4*)&Cb[(size_t)gm * TTIME + t0 + tx * 4] = r;
    }
}

// ---------------------------------------------------------------------------
// Summary attention scores: scores[b,h,l,t] = (sum_d qtok[l, h*128+d] * K[b,h*128+d,t]) / sqrt(128)
// block = (t-tile 64) x 4 d-quadrants; grid (T/64, NH, B)
// ---------------------------------------------------------------------------
__global__ __launch_bounds__(256) void sm_scores(
    const float* __restrict__ qtok, const float* __restrict__ K, float* __restrict__ scores)
{
    const int b = blockIdx.z, h = blockIdx.y, t0 = blockIdx.x * 64;
    __shared__ float qs[NTOK][128];
    __shared__ float red[4][NTOK][64];
    const int tid = threadIdx.x;
    for (int i = tid; i < NTOK * 128; i += 256) {
        int l = i >> 7, d = i & 127;
        qs[l][d] = qtok[l * FMC + h * 128 + d];
    }
    __syncthreads();
    const int lane = tid & 63, dq = tid >> 6;
    float sp[NTOK];
#pragma unroll
    for (int l = 0; l < NTOK; ++l) sp[l] = 0.f;
    const float* Kb = K + ((size_t)b * FMC + h * 128 + dq * 32) * TTIME + t0 + lane;
    for (int dd = 0; dd < 32; ++dd) {
        float kv = Kb[(size_t)dd * TTIME];
#pragma unroll
        for (int l = 0; l < NTOK; ++l) sp[l] += qs[l][dq * 32 + dd] * kv;
    }
#pragma unroll
    for (int l = 0; l < NTOK; ++l) red[dq][l][lane] = sp[l];
    __syncthreads();
    if (dq == 0) {
        for (int l = 0; l < NTOK; ++l) {
            float s = (red[0][l][lane] + red[1][l][lane] + red[2][l][lane] + red[3][l][lane])
                      * 0.08838834764831845f;
            scores[(((size_t)(b * NHEAD + h)) * NTOK + l) * TTIME + t0 + lane] = s;
        }
    }
}

// In-place row softmax, one block per row of length n
__global__ __launch_bounds__(256) void softmax_rows(float* __restrict__ p, int n)
{
    __shared__ float red[256];
    float* row = p + (size_t)blockIdx.x * n;
    const int tid = threadIdx.x;
    float mx = -1e30f;
    for (int t = tid; t < n; t += 256) mx = fmaxf(mx, row[t]);
    red[tid] = mx; __syncthreads();
    for (int s = 128; s > 0; s >>= 1) { if (tid < s) red[tid] = fmaxf(red[tid], red[tid + s]); __syncthreads(); }
    mx = red[0]; __syncthreads();
    float sum = 0.f;
    for (int t = tid; t < n; t += 256) { float e = expf(row[t] - mx); row[t] = e; sum += e; }
    red[tid] = sum; __syncthreads();
    for (int s = 128; s > 0; s >>= 1) { if (tid < s) red[tid] += red[tid + s]; __syncthreads(); }
    float inv = 1.0f / red[0];
    for (int t = tid; t < n; t += 256) row[t] *= inv;
}

// o[b,l,e] = sum_t att[b,h(e),l,t] * V[b,e,t]; one wave per (b,e)
__global__ __launch_bounds__(256) void sm_av(
    const float* __restrict__ att, const float* __restrict__ V, float* __restrict__ o)
{
    const int gw = blockIdx.x * 4 + (threadIdx.x >> 6);
    const int lane = threadIdx.x & 63;
    const int b = gw >> 9;
    const int e = gw & 511;
    const int h = e >> 7;
    float acc[NTOK] = {};
    const float* Vrow = V + ((size_t)b * FMC + e) * TTIME;
    const float* arow = att + ((size_t)(b * NHEAD + h)) * NTOK * TTIME;
    for (int t = lane; t < TTIME; t += 64) {
        float v = Vrow[t];
#pragma unroll
        for (int l = 0; l < NTOK; ++l) acc[l] += arow[(size_t)l * TTIME + t] * v;
    }
#pragma unroll
    for (int l = 0; l < NTOK; ++l) {
        float a = acc[l];
        for (int off = 32; off; off >>= 1) a += __shfl_down(a, off);
        if (lane == 0) o[((size_t)b * NTOK + l) * FMC + e] = a;
    }
}

// dst[r,e] = (accumulate? dst : 0) + bias[e] + sum_d in[r,d]*scale * W[e,d]
__global__ __launch_bounds__(256) void small_proj(
    const float* __restrict__ in, const float* __restrict__ W, const float* __restrict__ bias,
    float* __restrict__ dst, int E, int D, float scale, int accumulate)
{
    const int r = blockIdx.x;
    __shared__ float row[1024];
    const int tid = threadIdx.x;
    for (int d = tid; d < D; d += 256) row[d] = in[(size_t)r * D + d] * scale;
    __syncthreads();
    for (int e = tid; e < E; e += 256) {
        float acc = bias ? bias[e] : 0.f;
        const float* wr = W + (size_t)e * D;
        for (int d = 0; d < D; ++d) acc += row[d] * wr[d];
        if (accumulate) dst[(size_t)r * E + e] += acc;
        else            dst[(size_t)r * E + e] = acc;
    }
}

// Dilated 3-tap attention elementwise; H may alias Q (same-index read/write only)
__global__ __launch_bounds__(256) void dal_elem(
    const float* __restrict__ Q, const float* __restrict__ K, const float* __restrict__ V,
    const float* __restrict__ rel, float* __restrict__ H, int dil)
{
    const size_t idx = (size_t)blockIdx.x * 256 + threadIdx.x;
    const int t = (int)(idx & (TTIME - 1));
    const int c = (int)((idx >> 12) & (FMC - 1));
    float q = Q[idx];
    float k1 = K[idx], v1 = V[idx] + rel[c * 3 + 1];
    float k0 = 0.f, v0 = 0.f, k2 = 0.f, v2 = 0.f;
    if (t - dil >= 0) { k0 = K[idx - dil]; v0 = V[idx - dil]; }
    if (t + dil < TTIME) { k2 = K[idx + dil]; v2 = V[idx + dil]; }
    v0 += rel[c * 3 + 0];
    v2 += rel[c * 3 + 2];
    float s0 = q * k0, s1 = q * k1, s2 = q * k2;
    float m = fmaxf(s0, fmaxf(s1, s2));
    float e0 = expf(s0 - m), e1 = expf(s1 - m), e2 = expf(s2 - m);
    float h = (e0 * v0 + e1 * v1 + e2 * v2) / (e0 + e1 + e2);
    H[idx] = fmaxf(h, 0.f);
}

// Final cross-attention (queries = sequence, 10 keys), fused scores+softmax+AV.
// o_c[b, h*128+d, t] layout (B,FM,T). grid (T/64, NH, B), 256 threads.
__global__ __launch_bounds__(256) void ca_fused(
    const float* __restrict__ Qc, const float* __restrict__ khg, const float* __restrict__ vhg,
    float* __restrict__ o_c)
{
    const int b = blockIdx.z, h = blockIdx.y, t0 = blockIdx.x * 64;
    __shared__ float kh[NTOK][128];
    __shared__ float vh[NTOK][128];
    __shared__ float red[4][NTOK][64];
    const int tid = threadIdx.x;
    for (int i = tid; i < NTOK * 128; i += 256) {
        int l = i >> 7, d = i & 127;
        kh[l][d] = khg[((size_t)b * NTOK + l) * FMC + h * 128 + d];
        vh[l][d] = vhg[((size_t)b * NTOK + l) * FMC + h * 128 + d];
    }
    __syncthreads();
    const int lane = tid & 63, dq = tid >> 6;
    float sp[NTOK];
#pragma unroll
    for (int l = 0; l < NTOK; ++l) sp[l] = 0.f;
    const float* Qb = Qc + ((size_t)b * FMC + h * 128 + dq * 32) * TTIME + t0 + lane;
    for (int dd = 0; dd < 32; ++dd) {
        float qv = Qb[(size_t)dd * TTIME];
#pragma unroll
        for (int l = 0; l < NTOK; ++l) sp[l] += qv * kh[l][dq * 32 + dd];
    }
#pragma unroll
    for (int l = 0; l < NTOK; ++l) red[dq][l][lane] = sp[l];
    __syncthreads();
    // every thread recomputes the full score vector for its t, then softmax(10)
    float s[NTOK];
    float mx = -1e30f;
#pragma unroll
    for (int l = 0; l < NTOK; ++l) {
        s[l] = (red[0][l][lane] + red[1][l][lane] + red[2][l][lane] + red[3][l][lane])
               * 0.08838834764831845f;
        mx = fmaxf(mx, s[l]);
    }
    float sum = 0.f;
#pragma unroll
    for (int l = 0; l < NTOK; ++l) { s[l] = expf(s[l] - mx); sum += s[l]; }
    const float inv = 1.0f / sum;
    float* ob = o_c + ((size_t)b * FMC + h * 128 + dq * 32) * TTIME + t0 + lane;
    for (int dd = 0; dd < 32; ++dd) {
        float o = 0.f;
#pragma unroll
        for (int l = 0; l < NTOK; ++l) o += s[l] * vh[l][dq * 32 + dd];
        ob[(size_t)dd * TTIME] = o * inv;
    }
}

// ---------------------------------------------------------------------------
static inline void launch_gemm(const float* W, const float* X, float* C,
                               const float* bias, const float* resid, const float* mask,
                               int M, int K, hipStream_t s)
{
    dim3 grid(TTIME / BN, (M + BM - 1) / BM, BBATCH);
    dim3 block(256);
    if (bias && !resid && !mask)
        hipLaunchKernelGGL((gemm_wx<1, 0, 0>), grid, block, 0, s, W, X, C, bias, resid, mask, M, K);
    else if (!bias && !resid && !mask)
        hipLaunchKernelGGL((gemm_wx<0, 0, 0>), grid, block, 0, s, W, X, C, bias, resid, mask, M, K);
    else if (bias && resid && mask)
        hipLaunchKernelGGL((gemm_wx<1, 1, 1>), grid, block, 0, s, W, X, C, bias, resid, mask, M, K);
    else if (!bias && resid && !mask)
        hipLaunchKernelGGL((gemm_wx<0, 1, 0>), grid, block, 0, s, W, X, C, bias, resid, mask, M, K);
    else /* bias && !resid && mask */
        hipLaunchKernelGGL((gemm_wx<1, 0, 1>), grid, block, 0, s, W, X, C, bias, resid, mask, M, K);
}

extern "C" void kernel_launch(void* const* d_in, const int* in_sizes, int n_in,
                              void* d_out, int out_size, void* d_ws, size_t ws_size,
                              hipStream_t stream)
{
    const float* x        = (const float*)d_in[0];
    const float* mask     = (const float*)d_in[1];
    const float* cw1      = (const float*)d_in[2];
    const float* cb1      = (const float*)d_in[3];
    const float* dal_q    = (const float*)d_in[4];
    const float* dal_k    = (const float*)d_in[5];
    const float* dal_v    = (const float*)d_in[6];
    const float* rel_t    = (const float*)d_in[7];
    const float* blk_w    = (const float*)d_in[8];
    const float* blk_b    = (const float*)d_in[9];
    const float* cow      = (const float*)d_in[10];
    const float* cob      = (const float*)d_in[11];
    const float* tokens   = (const float*)d_in[12];
    const float* sm_in_w  = (const float*)d_in[13];
    const float* sm_in_b  = (const float*)d_in[14];
    const float* sm_out_w = (const float*)d_in[15];
    const float* sm_out_b = (const float*)d_in[16];
    const float* ca_in_w  = (const float*)d_in[17];
    const float* ca_out_w = (const float*)d_in[18];

    const size_t BIG = (size_t)BBATCH * FMC * TTIME; // 16.7M floats
    char* ws = (char*)d_ws;
    size_t off = 0;
    auto alloc = [&](size_t nfloats) {
        float* p = (float*)(ws + off);
        off += ((nfloats * 4) + 255) & ~(size_t)255;
        return p;
    };
    float* out     = alloc(BIG);
    float* buf0    = alloc(BIG);
    float* buf1    = alloc(BIG);
    float* buf2    = alloc(BIG);
    float* scores  = alloc((size_t)BBATCH * NHEAD * NTOK * TTIME);
    float* qtok    = alloc((size_t)NTOK * FMC);
    float* o_sm    = alloc((size_t)BBATCH * NTOK * FMC);
    float* summary = alloc((size_t)BBATCH * NTOK * FMC);
    float* kh_ca   = alloc((size_t)BBATCH * NTOK * FMC);
    float* vh_ca   = alloc((size_t)BBATCH * NTOK * FMC);
    (void)ws_size; (void)in_sizes; (void)n_in; (void)out_size;

    // Initial conv: out = cw1 @ x + cb1
    launch_gemm(cw1, x, out, cb1, nullptr, nullptr, FMC, DIMX, stream);

    // Token query projection (layer-invariant): qtok = tokens @ wq^T + bq
    hipLaunchKernelGGL(small_proj, dim3(NTOK), dim3(256), 0, stream,
                       tokens, sm_in_w, sm_in_b, qtok, FMC, FMC, 1.0f, 0);

    for (int i = 0; i < NLAYERS; ++i) {
        const int dil = 1 << i;
        // --- summary MHA (reads `out` before the dal update) ---
        launch_gemm(sm_in_w + (size_t)FMC * FMC, out, buf0, sm_in_b + FMC, nullptr, nullptr,
                    FMC, FMC, stream); // K
        launch_gemm(sm_in_w + (size_t)2 * FMC * FMC, out, buf1, sm_in_b + 2 * FMC, nullptr, nullptr,
                    FMC, FMC, stream); // V
        hipLaunchKernelGGL(sm_scores, dim3(TTIME / 64, NHEAD, BBATCH), dim3(256), 0, stream,
                           qtok, buf0, scores);
        hipLaunchKernelGGL(softmax_rows, dim3(BBATCH * NHEAD * NTOK), dim3(256), 0, stream,
                           scores, TTIME);
        hipLaunchKernelGGL(sm_av, dim3(BBATCH * FMC / 4), dim3(256), 0, stream,
                           scores, buf1, o_sm);
        hipLaunchKernelGGL(small_proj, dim3(BBATCH * NTOK), dim3(256), 0, stream,
                           o_sm, sm_out_w, sm_out_b, summary, FMC, FMC, 1.0f, (i > 0) ? 1 : 0);
        // --- dilated attention layer ---
        launch_gemm(dal_q + (size_t)i * FMC * FMC, out, buf0, nullptr, nullptr, nullptr, FMC, FMC, stream);
        launch_gemm(dal_k + (size_t)i * FMC * FMC, out, buf1, nullptr, nullptr, nullptr, FMC, FMC, stream);
        launch_gemm(dal_v + (size_t)i * FMC * FMC, out, buf2, nullptr, nullptr, nullptr, FMC, FMC, stream);
        hipLaunchKernelGGL(dal_elem, dim3((unsigned)(BIG / 256)), dim3(256), 0, stream,
                           buf0, buf1, buf2, rel_t + (size_t)i * FMC * 3, buf0, dil);
        // out = (out + blk_w @ h + blk_b) * mask
        launch_gemm(blk_w + (size_t)i * FMC * FMC, buf0, out, blk_b + (size_t)i * FMC, out, mask,
                    FMC, FMC, stream);
    }

    // --- final cross attention ---
    // Qc = wq_ca @ out  (B,FM,T)
    launch_gemm(ca_in_w, out, buf0, nullptr, nullptr, nullptr, FMC, FMC, stream);
    // kh/vh = (summary/5) @ w^T   (fold the /NUM_LAYERS scale in)
    hipLaunchKernelGGL(small_proj, dim3(BBATCH * NTOK), dim3(256), 0, stream,
                       summary, ca_in_w + (size_t)FMC * FMC, nullptr, kh_ca, FMC, FMC, 0.2f, 0);
    hipLaunchKernelGGL(small_proj, dim3(BBATCH * NTOK), dim3(256), 0, stream,
                       summary, ca_in_w + (size_t)2 * FMC * FMC, nullptr, vh_ca, FMC, FMC, 0.2f, 0);
    hipLaunchKernelGGL(ca_fused, dim3(TTIME / 64, NHEAD, BBATCH), dim3(256), 0, stream,
                       buf0, kh_ca, vh_ca, buf1);
    // out = out + ca_out_w @ o_c
    launch_gemm(ca_out_w, buf1, out, nullptr, out, nullptr, FMC, FMC, stream);
    // d_out = (cow @ out + cob) * mask
    launch_gemm(cow, out, (float*)d_out, cob, nullptr, mask, NCC, FMC, stream);
}

// Round 2
// 2099.253 us; speedup vs baseline: 4.8757x; 4.8757x over previous
//
#include <hip/hip_runtime.h>
#include <math.h>

#define FMC   512
#define DIMX  1024
#define NCC   157
#define NTOK  10
#define NHEAD 4
#define BBATCH 8
#define TTIME 4096
#define NLAYERS 5

typedef short bf16x8 __attribute__((ext_vector_type(8)));
typedef float f32x4v __attribute__((ext_vector_type(4)));
typedef unsigned short u16x8 __attribute__((ext_vector_type(8)));

__device__ __forceinline__ float b2f(unsigned short u){
    union { unsigned int i; float f; } v; v.i = ((unsigned int)u) << 16; return v.f;
}
__device__ __forceinline__ unsigned short f2b(float f){
    union { float f; unsigned int i; } v; v.f = f;
    unsigned int r = v.i + 0x7FFFu + ((v.i >> 16) & 1u);
    return (unsigned short)(r >> 16);
}

struct Outs5 { unsigned short* p[5]; };

// ---------------------------------------------------------------------------
// MFMA GEMM: C[b,t,m] = sum_k W[m,k] * X[b,t,k]   (all bf16, fp32 accumulate)
// Block 128m x 128t, BK=64, 4 waves (2x2), wave = 64x64 (4x4 MFMA 16x16x32).
// LDS XOR-swizzled [row][64] bf16 tiles (T2). Reg-staged 2-phase (T14-lite).
// Epilogue variants via template flags.
// ---------------------------------------------------------------------------
template<int HAS_BIAS,int HAS_RESID,int HAS_MASK,int WRITE_TRUNK,int SPLIT,int CMAJOR>
__global__ __launch_bounds__(256) void gemm_mfma(
    const unsigned short* __restrict__ W, const unsigned short* __restrict__ X,
    int M, int K,
    const float* __restrict__ bias, const float* __restrict__ trunkF_in,
    const float* __restrict__ mask,
    float* __restrict__ outF, unsigned short* __restrict__ outB,
    float* __restrict__ outCM, Outs5 outs)
{
    __shared__ __align__(16) unsigned short As[128 * 64];
    __shared__ __align__(16) unsigned short Xs[128 * 64];

    const int tid  = threadIdx.x;
    const int b    = blockIdx.z;
    const int m0   = blockIdx.y * 128;
    const int t0   = blockIdx.x * 128;
    const int wid  = tid >> 6, lane = tid & 63;
    const int wm   = (wid >> 1) * 64;   // wave m offset
    const int wt   = (wid & 1) * 64;    // wave t offset
    const int lanerow = lane & 15, laneoct = lane >> 4;

    // staging decode: 4 chunks of 16B per thread per tile
    int ldsOff[4]; int gWoff[4]; int gXoff[4]; int wGuard[4];
    #pragma unroll
    for (int it = 0; it < 4; ++it) {
        int idx = it * 256 + tid;
        int row = idx >> 3, c16 = idx & 7;
        ldsOff[it] = row * 64 + ((c16 * 8) ^ ((row & 7) * 8));   // ushort units
        gWoff[it]  = (m0 + row) * K + c16 * 8;
        gXoff[it]  = ((b * TTIME) + t0 + row) * K + c16 * 8;
        wGuard[it] = (m0 + row) < M;
    }

    f32x4v acc[4][4];
    #pragma unroll
    for (int i = 0; i < 4; ++i)
        #pragma unroll
        for (int j = 0; j < 4; ++j) { acc[i][j][0]=0.f; acc[i][j][1]=0.f; acc[i][j][2]=0.f; acc[i][j][3]=0.f; }

    u16x8 ra[4], rx[4];
    const u16x8 zz = {0,0,0,0,0,0,0,0};
    #pragma unroll
    for (int it = 0; it < 4; ++it) {
        ra[it] = (CMAJOR && !wGuard[it]) ? zz : *(const u16x8*)(W + gWoff[it]);
        rx[it] = *(const u16x8*)(X + (size_t)gXoff[it]);
    }

    const int nK = K >> 6;
    for (int ks = 0; ks < nK; ++ks) {
        #pragma unroll
        for (int it = 0; it < 4; ++it) {
            *(u16x8*)&As[ldsOff[it]] = ra[it];
            *(u16x8*)&Xs[ldsOff[it]] = rx[it];
        }
        __syncthreads();
        if (ks + 1 < nK) {
            const int k0 = (ks + 1) * 64;
            #pragma unroll
            for (int it = 0; it < 4; ++it) {
                ra[it] = (CMAJOR && !wGuard[it]) ? zz : *(const u16x8*)(W + gWoff[it] + k0);
                rx[it] = *(const u16x8*)(X + (size_t)gXoff[it] + k0);
            }
        }
        #pragma unroll
        for (int ksub = 0; ksub < 2; ++ksub) {
            const int xk = (ksub * 32 + laneoct * 8) ^ ((lanerow & 7) * 8);
            bf16x8 af[4], bfr[4];
            #pragma unroll
            for (int m = 0; m < 4; ++m)
                af[m] = *(const bf16x8*)&As[(wm + m * 16 + lanerow) * 64 + xk];
            #pragma unroll
            for (int n = 0; n < 4; ++n)
                bfr[n] = *(const bf16x8*)&Xs[(wt + n * 16 + lanerow) * 64 + xk];
            #pragma unroll
            for (int m = 0; m < 4; ++m)
                #pragma unroll
                for (int n = 0; n < 4; ++n)
                    acc[m][n] = __builtin_amdgcn_mfma_f32_16x16x32_bf16(af[m], bfr[n], acc[m][n], 0, 0, 0);
        }
        __syncthreads();
    }

    // epilogue: D row (m) = laneoct*4 + r, col (t) = lanerow
    #pragma unroll
    for (int msub = 0; msub < 4; ++msub) {
        const int mq = m0 + wm + msub * 16 + laneoct * 4;
        float b0 = 0.f, b1 = 0.f, b2 = 0.f, b3 = 0.f;
        if (HAS_BIAS) {
            if (CMAJOR) {
                b0 = (mq + 0 < M) ? bias[mq + 0] : 0.f;
                b1 = (mq + 1 < M) ? bias[mq + 1] : 0.f;
                b2 = (mq + 2 < M) ? bias[mq + 2] : 0.f;
                b3 = (mq + 3 < M) ? bias[mq + 3] : 0.f;
            } else {
                const float4 bq = *(const float4*)&bias[mq];
                b0 = bq.x; b1 = bq.y; b2 = bq.z; b3 = bq.w;
            }
        }
        #pragma unroll
        for (int tsub = 0; tsub < 4; ++tsub) {
            const int t = t0 + wt + tsub * 16 + lanerow;
            float v0 = acc[msub][tsub][0] + b0;
            float v1 = acc[msub][tsub][1] + b1;
            float v2 = acc[msub][tsub][2] + b2;
            float v3 = acc[msub][tsub][3] + b3;
            if (HAS_RESID) {
                const float4 rv = *(const float4*)&trunkF_in[((size_t)(b * TTIME + t)) * FMC + mq];
                v0 += rv.x; v1 += rv.y; v2 += rv.z; v3 += rv.w;
            }
            if (HAS_MASK) {
                const float mv = mask[b * TTIME + t];
                v0 *= mv; v1 *= mv; v2 *= mv; v3 *= mv;
            }
            if (CMAJOR) {
                if (mq + 0 < M) outCM[((size_t)(b * M + mq + 0)) * TTIME + t] = v0;
                if (mq + 1 < M) outCM[((size_t)(b * M + mq + 1)) * TTIME + t] = v1;
                if (mq + 2 < M) outCM[((size_t)(b * M + mq + 2)) * TTIME + t] = v2;
                if (mq + 3 < M) outCM[((size_t)(b * M + mq + 3)) * TTIME + t] = v3;
            } else {
                const unsigned long long pk =
                    (unsigned long long)f2b(v0) | ((unsigned long long)f2b(v1) << 16) |
                    ((unsigned long long)f2b(v2) << 32) | ((unsigned long long)f2b(v3) << 48);
                if (WRITE_TRUNK) {
                    float4 fv; fv.x = v0; fv.y = v1; fv.z = v2; fv.w = v3;
                    *(float4*)&outF[((size_t)(b * TTIME + t)) * FMC + mq] = fv;
                    *(unsigned long long*)(outB + ((size_t)(b * TTIME + t)) * FMC + mq) = pk;
                } else if (SPLIT) {
                    const int sel = blockIdx.y >> 2;
                    const int mi = mq - sel * FMC;
                    *(unsigned long long*)(outs.p[sel] + ((size_t)(b * TTIME + t)) * FMC + mi) = pk;
                } else {
                    *(unsigned long long*)(outB + ((size_t)(b * TTIME + t)) * FMC + mq) = pk;
                }
            }
        }
    }
}

// ---------------------------------------------------------------------------
// x (B,1024,T) f32 -> xT (B,T,1024) bf16
// ---------------------------------------------------------------------------
__global__ __launch_bounds__(256) void transpose_x(
    const float* __restrict__ x, unsigned short* __restrict__ xT)
{
    __shared__ float tile[64][65];
    const int b = blockIdx.z, d0 = blockIdx.y * 64, t0 = blockIdx.x * 64;
    const int tx = threadIdx.x & 63, ty = threadIdx.x >> 6;
    #pragma unroll
    for (int i = 0; i < 64; i += 4)
        tile[ty + i][tx] = x[((size_t)(b * DIMX + d0 + ty + i)) * TTIME + t0 + tx];
    __syncthreads();
    #pragma unroll
    for (int i = 0; i < 64; i += 4)
        xT[((size_t)(b * TTIME + t0 + ty + i)) * DIMX + d0 + tx] = f2b(tile[tx][ty + i]);
}

// generic f32 -> bf16
__global__ void to_bf16(const float* __restrict__ s, unsigned short* __restrict__ d, int n)
{
    for (int i = blockIdx.x * 256 + threadIdx.x; i < n; i += gridDim.x * 256)
        d[i] = f2b(s[i]);
}

// Wcat[i][r][c]: r<512: wk ; r<1024: wv ; r<1536: dal_q[i] ; <2048: dal_k[i] ; else dal_v[i]
__global__ void build_wcat(const float* __restrict__ sm_in_w,
                           const float* __restrict__ dq, const float* __restrict__ dk,
                           const float* __restrict__ dv, unsigned short* __restrict__ Wcat)
{
    const int total = NLAYERS * 2560 * 512;
    for (int idx = blockIdx.x * 256 + threadIdx.x; idx < total; idx += gridDim.x * 256) {
        const int i = idx / (2560 * 512);
        const int r = (idx >> 9) % 2560;
        const int c = idx & 511;
        float v;
        if (r < 1024)       v = sm_in_w[(size_t)(512 + r) * 512 + c];
        else if (r < 1536)  v = dq[((size_t)i * 512 + (r - 1024)) * 512 + c];
        else if (r < 2048)  v = dk[((size_t)i * 512 + (r - 1536)) * 512 + c];
        else                v = dv[((size_t)i * 512 + (r - 2048)) * 512 + c];
        Wcat[idx] = f2b(v);
    }
}

__global__ void build_bcat(const float* __restrict__ sm_in_b, float* __restrict__ bcat)
{
    const int r = blockIdx.x * 256 + threadIdx.x;
    if (r < 2560) bcat[r] = (r < 1024) ? sm_in_b[512 + r] : 0.f;
}

// ---------------------------------------------------------------------------
// scores[b,h,l,t] = (sum_d qtok[l,h*128+d] * kh[b,t,h*128+d]) / sqrt(128)
// ---------------------------------------------------------------------------
__global__ __launch_bounds__(256) void sm_scores_t(
    const float* __restrict__ qtok, const unsigned short* __restrict__ kh,
    float* __restrict__ scores)
{
    const int b = blockIdx.z, h = blockIdx.y;
    __shared__ float qs[NTOK][128];
    for (int i = threadIdx.x; i < NTOK * 128; i += 256)
        qs[i >> 7][i & 127] = qtok[(i >> 7) * FMC + h * 128 + (i & 127)];
    __syncthreads();
    const int t = blockIdx.x * 256 + threadIdx.x;
    const unsigned short* kp = kh + ((size_t)(b * TTIME + t)) * FMC + h * 128;
    float s[NTOK];
    #pragma unroll
    for (int l = 0; l < NTOK; ++l) s[l] = 0.f;
    #pragma unroll
    for (int d0 = 0; d0 < 128; d0 += 8) {
        const u16x8 kv = *(const u16x8*)(kp + d0);
        float kf[8];
        #pragma unroll
        for (int j = 0; j < 8; ++j) kf[j] = b2f((unsigned short)kv[j]);
        #pragma unroll
        for (int l = 0; l < NTOK; ++l) {
            float a = 0.f;
            #pragma unroll
            for (int j = 0; j < 8; ++j) a += kf[j] * qs[l][d0 + j];
            s[l] += a;
        }
    }
    #pragma unroll
    for (int l = 0; l < NTOK; ++l)
        scores[(((size_t)(b * NHEAD + h)) * NTOK + l) * TTIME + t] = s[l] * 0.08838834764831845f;
}

__global__ __launch_bounds__(256) void softmax_rows(float* __restrict__ p, int n)
{
    __shared__ float red[256];
    float* row = p + (size_t)blockIdx.x * n;
    const int tid = threadIdx.x;
    float mx = -1e30f;
    for (int t = tid; t < n; t += 256) mx = fmaxf(mx, row[t]);
    red[tid] = mx; __syncthreads();
    for (int s = 128; s > 0; s >>= 1) { if (tid < s) red[tid] = fmaxf(red[tid], red[tid + s]); __syncthreads(); }
    mx = red[0]; __syncthreads();
    float sum = 0.f;
    for (int t = tid; t < n; t += 256) { float e = __expf(row[t] - mx); row[t] = e; sum += e; }
    red[tid] = sum; __syncthreads();
    for (int s = 128; s > 0; s >>= 1) { if (tid < s) red[tid] += red[tid + s]; __syncthreads(); }
    const float inv = 1.0f / red[0];
    for (int t = tid; t < n; t += 256) row[t] *= inv;
}

// o_sm[b,l,e] += sum_t att[b,h(e),l,t] * vh[b,t,e]   (atomic over t-segments)
__global__ __launch_bounds__(256) void sm_av_cl(
    const float* __restrict__ att, const unsigned short* __restrict__ vh,
    float* __restrict__ o_sm)
{
    const int tseg = blockIdx.x, ch = blockIdx.y, b = blockIdx.z;
    const int ei = threadIdx.x & 63, tg = threadIdx.x >> 6;
    const int e = ch * 64 + ei, h = e >> 7;
    float a[NTOK];
    #pragma unroll
    for (int l = 0; l < NTOK; ++l) a[l] = 0.f;
    const int tbase = tseg * 256 + tg * 64;
    for (int tt = 0; tt < 64; ++tt) {
        const int t = tbase + tt;
        const float v = b2f(vh[((size_t)(b * TTIME + t)) * FMC + e]);
        #pragma unroll
        for (int l = 0; l < NTOK; ++l)
            a[l] += att[(((size_t)(b * NHEAD + h)) * NTOK + l) * TTIME + t] * v;
    }
    __shared__ float red[4][NTOK][64];
    #pragma unroll
    for (int l = 0; l < NTOK; ++l) red[tg][l][ei] = a[l];
    __syncthreads();
    if (tg == 0) {
        #pragma unroll
        for (int l = 0; l < NTOK; ++l) {
            const float s = red[0][l][ei] + red[1][l][ei] + red[2][l][ei] + red[3][l][ei];
            atomicAdd(&o_sm[((size_t)(b * NTOK) + l) * FMC + e], s);
        }
    }
}

// dst[r,e] = (accumulate? dst : 0) + bias[e] + sum_d in[r,d]*scale * W[e,d]   (fp32)
__global__ __launch_bounds__(256) void small_proj(
    const float* __restrict__ in, const float* __restrict__ W, const float* __restrict__ bias,
    float* __restrict__ dst, int E, int D, float scale, int accumulate)
{
    const int r = blockIdx.x;
    __shared__ float row[1024];
    const int tid = threadIdx.x;
    for (int d = tid; d < D; d += 256) row[d] = in[(size_t)r * D + d] * scale;
    __syncthreads();
    for (int e = tid; e < E; e += 256) {
        float acc = bias ? bias[e] : 0.f;
        const float* wr = W + (size_t)e * D;
        for (int d = 0; d < D; ++d) acc += row[d] * wr[d];
        if (accumulate) dst[(size_t)r * E + e] += acc;
        else            dst[(size_t)r * E + e] = acc;
    }
}

// dilated 3-tap attention, channel-last bf16; H may alias Q
__global__ __launch_bounds__(256) void dal_elem_cl(
    const unsigned short* __restrict__ Q, const unsigned short* __restrict__ K,
    const unsigned short* __restrict__ V, const float* __restrict__ rel,
    unsigned short* __restrict__ H, int dil)
{
    __shared__ float rels[FMC * 3];
    for (int i = threadIdx.x; i < FMC * 3; i += 256) rels[i] = rel[i];
    __syncthreads();
    const int g = blockIdx.x * 256 + threadIdx.x;
    const int c8 = g & 63;
    const int t = (g >> 6) & (TTIME - 1);
    const int b = g >> 18;
    const size_t base = ((size_t)(b * TTIME + t)) * FMC + c8 * 8;
    const u16x8 q8 = *(const u16x8*)(Q + base);
    const u16x8 k1 = *(const u16x8*)(K + base);
    const u16x8 v1 = *(const u16x8*)(V + base);
    u16x8 k0 = {0,0,0,0,0,0,0,0}, v0 = k0, k2 = k0, v2 = k0;
    const bool in0 = (t - dil) >= 0, in2 = (t + dil) < TTIME;
    if (in0) { k0 = *(const u16x8*)(K + base - (size_t)dil * FMC); v0 = *(const u16x8*)(V + base - (size_t)dil * FMC); }
    if (in2) { k2 = *(const u16x8*)(K + base + (size_t)dil * FMC); v2 = *(const u16x8*)(V + base + (size_t)dil * FMC); }
    u16x8 out;
    #pragma unroll
    for (int j = 0; j < 8; ++j) {
        const int c = c8 * 8 + j;
        const float q = b2f((unsigned short)q8[j]);
        const float kk0 = b2f((unsigned short)k0[j]);
        const float kk1 = b2f((unsigned short)k1[j]);
        const float kk2 = b2f((unsigned short)k2[j]);
        const float vv0 = b2f((unsigned short)v0[j]) + rels[c * 3 + 0];
        const float vv1 = b2f((unsigned short)v1[j]) + rels[c * 3 + 1];
        const float vv2 = b2f((unsigned short)v2[j]) + rels[c * 3 + 2];
        const float s0 = q * kk0, s1 = q * kk1, s2 = q * kk2;
        const float m = fmaxf(s0, fmaxf(s1, s2));
        const float e0 = __expf(s0 - m), e1 = __expf(s1 - m), e2 = __expf(s2 - m);
        const float hres = (e0 * vv0 + e1 * vv1 + e2 * vv2) / (e0 + e1 + e2);
        out[j] = (short)f2b(fmaxf(hres, 0.f));
    }
    *(u16x8*)(H + base) = out;
}

// final cross attention: per (b,h,t): scores vs 10 keys -> softmax -> AV
__global__ __launch_bounds__(256) void ca_fused_t(
    const unsigned short* __restrict__ Qc, const float* __restrict__ khg,
    const float* __restrict__ vhg, unsigned short* __restrict__ o_c)
{
    const int b = blockIdx.z, h = blockIdx.y;
    __shared__ float kh[NTOK][128];
    __shared__ float vh[NTOK][128];
    for (int i = threadIdx.x; i < NTOK * 128; i += 256) {
        const int l = i >> 7, d = i & 127;
        kh[l][d] = khg[((size_t)(b * NTOK) + l) * FMC + h * 128 + d];
        vh[l][d] = vhg[((size_t)(b * NTOK) + l) * FMC + h * 128 + d];
    }
    __syncthreads();
    const int t = blockIdx.x * 256 + threadIdx.x;
    const unsigned short* qp = Qc + ((size_t)(b * TTIME + t)) * FMC + h * 128;
    float s[NTOK];
    #pragma unroll
    for (int l = 0; l < NTOK; ++l) s[l] = 0.f;
    #pragma unroll
    for (int d0 = 0; d0 < 128; d0 += 8) {
        const u16x8 qv = *(const u16x8*)(qp + d0);
        float qf[8];
        #pragma unroll
        for (int j = 0; j < 8; ++j) qf[j] = b2f((unsigned short)qv[j]);
        #pragma unroll
        for (int l = 0; l < NTOK; ++l) {
            float a = 0.f;
            #pragma unroll
            for (int j = 0; j < 8; ++j) a += qf[j] * kh[l][d0 + j];
            s[l] += a;
        }
    }
    float mx = -1e30f;
    #pragma unroll
    for (int l = 0; l < NTOK; ++l) { s[l] *= 0.08838834764831845f; mx = fmaxf(mx, s[l]); }
    float sum = 0.f;
    #pragma unroll
    for (int l = 0; l < NTOK; ++l) { s[l] = __expf(s[l] - mx); sum += s[l]; }
    const float inv = 1.0f / sum;
    #pragma unroll
    for (int l = 0; l < NTOK; ++l) s[l] *= inv;
    unsigned short* op = o_c + ((size_t)(b * TTIME + t)) * FMC + h * 128;
    #pragma unroll
    for (int d0 = 0; d0 < 128; d0 += 8) {
        u16x8 o8;
        #pragma unroll
        for (int j = 0; j < 8; ++j) {
            float o = 0.f;
            #pragma unroll
            for (int l = 0; l < NTOK; ++l) o += s[l] * vh[l][d0 + j];
            o8[j] = (short)f2b(o);
        }
        *(u16x8*)(op + d0) = o8;
    }
}

// ---------------------------------------------------------------------------
extern "C" void kernel_launch(void* const* d_in, const int* in_sizes, int n_in,
                              void* d_out, int out_size, void* d_ws, size_t ws_size,
                              hipStream_t stream)
{
    const float* x        = (const float*)d_in[0];
    const float* mask     = (const float*)d_in[1];
    const float* cw1      = (const float*)d_in[2];
    const float* cb1      = (const float*)d_in[3];
    const float* dal_q    = (const float*)d_in[4];
    const float* dal_k    = (const float*)d_in[5];
    const float* dal_v    = (const float*)d_in[6];
    const float* rel_t    = (const float*)d_in[7];
    const float* blk_w    = (const float*)d_in[8];
    const float* blk_b    = (const float*)d_in[9];
    const float* cow      = (const float*)d_in[10];
    const float* cob      = (const float*)d_in[11];
    const float* tokens   = (const float*)d_in[12];
    const float* sm_in_w  = (const float*)d_in[13];
    const float* sm_in_b  = (const float*)d_in[14];
    const float* sm_out_w = (const float*)d_in[15];
    const float* sm_out_b = (const float*)d_in[16];
    const float* ca_in_w  = (const float*)d_in[17];
    const float* ca_out_w = (const float*)d_in[18];
    (void)in_sizes; (void)n_in; (void)out_size; (void)ws_size;

    const size_t BIG = (size_t)BBATCH * FMC * TTIME;   // 16.7M elems
    char* ws = (char*)d_ws;
    size_t off = 0;
    auto alloc = [&](size_t nbytes) {
        void* p = (void*)(ws + off);
        off = (off + nbytes + 255) & ~(size_t)255;
        return p;
    };
    float*          trunkF  = (float*)alloc(BIG * 4);
    unsigned short* trunkB  = (unsigned short*)alloc(BIG * 2);
    unsigned short* bufA    = (unsigned short*)alloc(BIG * 2);   // kh / (xT low half) / o_c? no: kh
    unsigned short* bufB    = (unsigned short*)alloc(BIG * 2);   // vh / (xT high half)
    unsigned short* bufC    = (unsigned short*)alloc(BIG * 2);   // q -> h -> Qc
    unsigned short* bufD    = (unsigned short*)alloc(BIG * 2);   // k -> o_c
    unsigned short* bufE    = (unsigned short*)alloc(BIG * 2);   // v
    float* scores  = (float*)alloc((size_t)BBATCH * NHEAD * NTOK * TTIME * 4);
    float* qtok    = (float*)alloc((size_t)NTOK * FMC * 4);
    float* o_sm    = (float*)alloc((size_t)BBATCH * NTOK * FMC * 4);
    float* summary = (float*)alloc((size_t)BBATCH * NTOK * FMC * 4);
    float* kh_ca   = (float*)alloc((size_t)BBATCH * NTOK * FMC * 4);
    float* vh_ca   = (float*)alloc((size_t)BBATCH * NTOK * FMC * 4);
    unsigned short* Wc   = (unsigned short*)alloc((size_t)FMC * DIMX * 2);
    unsigned short* Wcat = (unsigned short*)alloc((size_t)NLAYERS * 2560 * FMC * 2);
    unsigned short* Wblk = (unsigned short*)alloc((size_t)NLAYERS * FMC * FMC * 2);
    unsigned short* Wqca = (unsigned short*)alloc((size_t)FMC * FMC * 2);
    unsigned short* Wcao = (unsigned short*)alloc((size_t)FMC * FMC * 2);
    unsigned short* Wcow = (unsigned short*)alloc((size_t)NCC * FMC * 2);
    float* bcat = (float*)alloc(2560 * 4);
    unsigned short* xT = bufA;  // spans bufA+bufB (B*T*1024 bf16), dead after conv

    const Outs5 no5 = {};

    // --- weight conversion ---
    hipLaunchKernelGGL(to_bf16, dim3(512), dim3(256), 0, stream, cw1, Wc, FMC * DIMX);
    hipLaunchKernelGGL(to_bf16, dim3(512), dim3(256), 0, stream, ca_in_w, Wqca, FMC * FMC);
    hipLaunchKernelGGL(to_bf16, dim3(512), dim3(256), 0, stream, ca_out_w, Wcao, FMC * FMC);
    hipLaunchKernelGGL(to_bf16, dim3(128), dim3(256), 0, stream, cow, Wcow, NCC * FMC);
    hipLaunchKernelGGL(to_bf16, dim3(1024), dim3(256), 0, stream, blk_w, Wblk, NLAYERS * FMC * FMC);
    hipLaunchKernelGGL(build_wcat, dim3(2048), dim3(256), 0, stream, sm_in_w, dal_q, dal_k, dal_v, Wcat);
    hipLaunchKernelGGL(build_bcat, dim3(10), dim3(256), 0, stream, sm_in_b, bcat);

    // --- input transpose to channel-last bf16 ---
    hipLaunchKernelGGL(transpose_x, dim3(TTIME / 64, DIMX / 64, BBATCH), dim3(256), 0, stream, x, xT);

    // --- conv: trunk = cw1 @ x + cb1 ---
    hipLaunchKernelGGL((gemm_mfma<1,0,0,1,0,0>), dim3(TTIME / 128, FMC / 128, BBATCH), dim3(256), 0, stream,
                       Wc, xT, FMC, DIMX, cb1, nullptr, nullptr, trunkF, trunkB, nullptr, no5);

    // --- token query projection ---
    hipLaunchKernelGGL(small_proj, dim3(NTOK), dim3(256), 0, stream,
                       tokens, sm_in_w, sm_in_b, qtok, FMC, FMC, 1.0f, 0);

    for (int i = 0; i < NLAYERS; ++i) {
        const int dil = 1 << i;
        // fused 5-way projection: {kh, vh, q, k, v} = Wcat[i] @ trunk
        Outs5 o5; o5.p[0] = bufA; o5.p[1] = bufB; o5.p[2] = bufC; o5.p[3] = bufD; o5.p[4] = bufE;
        hipLaunchKernelGGL((gemm_mfma<1,0,0,0,1,0>), dim3(TTIME / 128, 20, BBATCH), dim3(256), 0, stream,
                           Wcat + (size_t)i * 2560 * FMC, trunkB, 2560, FMC,
                           bcat, nullptr, nullptr, nullptr, nullptr, nullptr, o5);
        // summary MHA
        hipLaunchKernelGGL(sm_scores_t, dim3(TTIME / 256, NHEAD, BBATCH), dim3(256), 0, stream,
                           qtok, bufA, scores);
        hipLaunchKernelGGL(softmax_rows, dim3(BBATCH * NHEAD * NTOK), dim3(256), 0, stream,
                           scores, TTIME);
        hipMemsetAsync(o_sm, 0, (size_t)BBATCH * NTOK * FMC * 4, stream);
        hipLaunchKernelGGL(sm_av_cl, dim3(16, 8, BBATCH), dim3(256), 0, stream,
                           scores, bufB, o_sm);
        hipLaunchKernelGGL(small_proj, dim3(BBATCH * NTOK), dim3(256), 0, stream,
                           o_sm, sm_out_w, sm_out_b, summary, FMC, FMC, 1.0f, (i > 0) ? 1 : 0);
        // dilated attention (h aliases q in bufC)
        hipLaunchKernelGGL(dal_elem_cl, dim3((unsigned)(BIG / 256 / 8)), dim3(256), 0, stream,
                           bufC, bufD, bufE, rel_t + (size_t)i * FMC * 3, bufC, dil);
        // trunk = (trunk + blk_w @ h + blk_b) * mask
        hipLaunchKernelGGL((gemm_mfma<1,1,1,1,0,0>), dim3(TTIME / 128, FMC / 128, BBATCH), dim3(256), 0, stream,
                           Wblk + (size_t)i * FMC * FMC, bufC, FMC, FMC,
                           blk_b + (size_t)i * FMC, trunkF, mask, trunkF, trunkB, nullptr, no5);
    }

    // --- final cross attention ---
    hipLaunchKernelGGL((gemm_mfma<0,0,0,0,0,0>), dim3(TTIME / 128, FMC / 128, BBATCH), dim3(256), 0, stream,
                       Wqca, trunkB, FMC, FMC, nullptr, nullptr, nullptr, nullptr, bufC, nullptr, no5);
    hipLaunchKernelGGL(small_proj, dim3(BBATCH * NTOK), dim3(256), 0, stream,
                       summary, ca_in_w + (size_t)FMC * FMC, nullptr, kh_ca, FMC, FMC, 0.2f, 0);
    hipLaunchKernelGGL(small_proj, dim3(BBATCH * NTOK), dim3(256), 0, stream,
                       summary, ca_in_w + (size_t)2 * FMC * FMC, nullptr, vh_ca, FMC, FMC, 0.2f, 0);
    hipLaunchKernelGGL(ca_fused_t, dim3(TTIME / 256, NHEAD, BBATCH), dim3(256), 0, stream,
                       bufC, kh_ca, vh_ca, bufD);
    // trunk += ca_out_w @ o_c
    hipLaunchKernelGGL((gemm_mfma<0,1,0,1,0,0>), dim3(TTIME / 128, FMC / 128, BBATCH), dim3(256), 0, stream,
                       Wcao, bufD, FMC, FMC, nullptr, trunkF, nullptr, trunkF, trunkB, nullptr, no5);
    // d_out = (cow @ trunk + cob) * mask   (channel-major fp32)
    hipLaunchKernelGGL((gemm_mfma<1,0,1,0,0,1>), dim3(TTIME / 128, 2, BBATCH), dim3(256), 0, stream,
                       Wcow, trunkB, NCC, FMC, cob, nullptr, mask, nullptr, nullptr, (float*)d_out, no5);
}